// Round 12
// baseline (721.909 us; speedup 1.0000x reference)
//
#include <hip/hip_runtime.h>
#include <hip/hip_bf16.h>

// Problem constants (fixed by setup_inputs)
#define F_DIM   128
#define PER_DEG 50000
#define NDEG    11
#define MAXD    10
#define BATCH   4096
#define N_ATOMS (PER_DEG * NDEG)

// Tile config
#define BM     64
#define LDSN   136                       // 128 + 8 pad shorts (nbr half only)
#define BPD    ((PER_DEG + BM - 1) / BM) // 782 blocks per degree
#define WT_K   256                       // main kernel: [Wnbr;Wself]
#define GWT_K  1440                      // gat GEMM: 11*128 feats + 11 counts + pad
#define LDST_L 264                       // legacy fallback stride
#define WT_K_L 384                       // legacy fallback wt K

#define GATHER_BLKS (NDEG * BPD)                 // 8602
#define MOL_BLKS    ((BATCH * NDEG) / 2)         // 22528 (2 keys per block)
#define ALL_BLKS    (GATHER_BLKS + MOL_BLKS)     // 31130

typedef __attribute__((ext_vector_type(4))) float f32x4;
typedef __attribute__((ext_vector_type(8))) short short8v;
typedef __attribute__((ext_vector_type(4))) short short4v;

struct AdjPtrs { const int* p[MAXD]; };

__device__ inline short bf16bits(float x) {
    __hip_bfloat16 h = __float2bfloat16(x);
    return __builtin_bit_cast(short, h);
}
__device__ inline float bf_lo(unsigned u) { return __builtin_bit_cast(float, u << 16); }
__device__ inline float bf_hi(unsigned u) { return __builtin_bit_cast(float, u & 0xFFFF0000u); }
__device__ inline float bf2f(short s) {
    return __builtin_bit_cast(float, ((unsigned)(unsigned short)s) << 16);
}
// int8 quantization: q = rint(x*16), clamp [-127,127]; decode q*0.0625
__device__ inline unsigned enc4_i8(float x0, float x1, float x2, float x3) {
    int q0 = (int)rintf(x0 * 16.0f), q1 = (int)rintf(x1 * 16.0f);
    int q2 = (int)rintf(x2 * 16.0f), q3 = (int)rintf(x3 * 16.0f);
    q0 = max(-127, min(127, q0)); q1 = max(-127, min(127, q1));
    q2 = max(-127, min(127, q2)); q3 = max(-127, min(127, q3));
    return (unsigned)(q0 & 255) | ((unsigned)(q1 & 255) << 8) |
           ((unsigned)(q2 & 255) << 16) | ((unsigned)(q3 & 255) << 24);
}
__device__ inline int sbyte(unsigned w, int k) {      // sign-extended byte k
    return (int)(w << (24 - 8 * k)) >> 24;
}

// ---------- weight prep: wt[d][c][k], k in [0,256) = [Wnbr;Wself] ----------
__global__ void prep_wt_main(const float* __restrict__ W, short* __restrict__ wt) {
    int idx = blockIdx.x * blockDim.x + threadIdx.x;
    const int total = NDEG * F_DIM * WT_K;
    if (idx >= total) return;
    int d   = idx / (F_DIM * WT_K);
    int rem = idx % (F_DIM * WT_K);
    int c   = rem / WT_K;
    int k   = rem % WT_K;
    float v;
    if (d == 0) {
        v = (k < 128) ? 0.0f : W[20 * 16384 + (k - 128) * F_DIM + c];
    } else {
        int wi = (k < 128) ? (2 * (d - 1)) : (2 * (d - 1) + 1);
        v = W[wi * 16384 + (k & 127) * F_DIM + c];
    }
    wt[idx] = bf16bits(v);
}

// ---------- gat GEMM weights: gwt[c][k], K=1440 (feats | gb-row | zeros) ----
__global__ void prep_gwt(const float* __restrict__ gW, const float* __restrict__ gb,
                         short* __restrict__ gwt) {
    int idx = blockIdx.x * blockDim.x + threadIdx.x;
    const int total = F_DIM * GWT_K;
    if (idx >= total) return;
    int c = idx / GWT_K;
    int k = idx % GWT_K;
    float v = 0.0f;
    if (k < 1408) {
        int dd = k >> 7, f = k & 127;
        int gi = dd ? (dd - 1) : 10;
        v = gW[gi * 16384 + f * F_DIM + c];
    } else if (k < 1419) {
        int dd = k - 1408;
        int gi = dd ? (dd - 1) : 10;
        v = gb[gi * F_DIM + c];
    }
    gwt[idx] = bf16bits(v);
}

// ---------- one-time atoms f32 -> int8 table (70.4 MB) ----------------------
__global__ void to_i8(const float* __restrict__ in, unsigned char* __restrict__ out8) {
    const size_t n8 = (size_t)N_ATOMS * F_DIM / 8;
    size_t stride = (size_t)gridDim.x * blockDim.x;
    for (size_t k = (size_t)blockIdx.x * blockDim.x + threadIdx.x; k < n8; k += stride) {
        f32x4 a = __builtin_nontemporal_load((const f32x4*)in + 2 * k);
        f32x4 c = __builtin_nontemporal_load((const f32x4*)in + 2 * k + 1);
        uint2 u;
        u.x = enc4_i8(a[0], a[1], a[2], a[3]);
        u.y = enc4_i8(c[0], c[1], c[2], c[3]);
        ((uint2*)out8)[k] = u;
    }
}

// ---------- inverted index over (molecule, degree) keys --------------------
__global__ void hist_kernel(const int* __restrict__ mem, int* __restrict__ hist2) {
    int i = blockIdx.x * blockDim.x + threadIdx.x;
    if (i >= N_ATOMS) return;
    atomicAdd(&hist2[mem[i] * NDEG + i / PER_DEG], 1);
}

__global__ void scan_offsets(const int* __restrict__ hist2,
                             int* __restrict__ off, int* __restrict__ cur) {
    __shared__ int lds[1024];
    const int tid = threadIdx.x;
    int h[4][NDEG];
    int tsum = 0;
    #pragma unroll
    for (int mi = 0; mi < 4; ++mi) {
        int m = tid * 4 + mi;
        #pragma unroll
        for (int dd = 0; dd < NDEG; ++dd) { h[mi][dd] = hist2[m * NDEG + dd]; tsum += h[mi][dd]; }
    }
    lds[tid] = tsum;
    __syncthreads();
    for (int ofs = 1; ofs < 1024; ofs <<= 1) {
        int v = (tid >= ofs) ? lds[tid - ofs] : 0;
        __syncthreads();
        lds[tid] += v;
        __syncthreads();
    }
    int run = lds[tid] - tsum;   // exclusive prefix
    #pragma unroll
    for (int mi = 0; mi < 4; ++mi) {
        int m = tid * 4 + mi;
        #pragma unroll
        for (int dd = 0; dd < NDEG; ++dd) {
            int k = m * NDEG + dd;
            off[k] = run; cur[k] = run;
            run += h[mi][dd];
        }
    }
}

__global__ void scatter_kernel(const int* __restrict__ mem,
                               int* __restrict__ cur, int* __restrict__ idx) {
    int i = blockIdx.x * blockDim.x + threadIdx.x;
    if (i >= N_ATOMS) return;
    int pos = atomicAdd(&cur[mem[i] * NDEG + i / PER_DEG], 1);
    idx[pos] = i;
}

// ---------- merged kernel: gather/MFMA blocks + mol-reduce blocks -----------
// R11: fused_deg (latency-bound, pipes idle) and mol_reduce (latency-bound,
// independent) share one dispatch; Bresenham role interleave keeps both
// co-resident so mol's random reads hide in gather's idle memory slots.
// Gather path unchanged from R10 (int8 table, depth-3 pipeline, 4 blocks/CU).
__global__ __launch_bounds__(256, 4) void fused_all(
    const unsigned char* __restrict__ ai8,
    const float* __restrict__ atoms,
    AdjPtrs adj,
    const short* __restrict__ wt,
    const float* __restrict__ b,
    const float* __restrict__ gamma,
    const float* __restrict__ beta,
    const int* __restrict__ idx,
    const int* __restrict__ off,
    const int* __restrict__ hist2,
    float* __restrict__ outN,
    short* __restrict__ sums)
{
    __shared__ short As[BM * LDSN];
    const int bid = blockIdx.x;
    const int tid = threadIdx.x;

    // Bresenham interleave: gather blocks at density GATHER_BLKS/ALL_BLKS
    const int i0 = (int)(((long long)bid * GATHER_BLKS) / ALL_BLKS);
    const int i1 = (int)(((long long)(bid + 1) * GATHER_BLKS) / ALL_BLKS);

    if (i1 > i0) {
        // ================= gather/MFMA block #i0 =================
        const int d     = i0 % NDEG;      // degree-interleaved
        const int rb    = i0 / NDEG;
        const int rows0 = rb * BM;

        {
            const int rloc = tid >> 2;
            const int p    = tid & 3;
            const int grow = rows0 + rloc;
            short* basep = &As[rloc * LDSN + p * 32];
            int acci[32];
            #pragma unroll
            for (int e = 0; e < 32; ++e) acci[e] = 0;
            if (grow < PER_DEG && d > 0) {
                const int* ar = adj.p[d - 1] + (size_t)grow * d;
                int idxs[MAXD];
                #pragma unroll
                for (int j = 0; j < MAXD; ++j) idxs[j] = (j < d) ? ar[j] : 0;
                uint4 b0x, b0y, b1x, b1y, b2x, b2y;
                {
                    const uint4* r0 = (const uint4*)(ai8 + (size_t)idxs[0] * F_DIM) + p * 2;
                    b0x = r0[0]; b0y = r0[1];
                }
                if (d > 1) {
                    const uint4* r1 = (const uint4*)(ai8 + (size_t)idxs[1] * F_DIM) + p * 2;
                    b1x = r1[0]; b1y = r1[1];
                }
                #pragma unroll
                for (int j = 0; j < MAXD; ++j) {
                    if (j < d) {
                        if (j + 2 < d) {
                            const uint4* rn =
                                (const uint4*)(ai8 + (size_t)idxs[j + 2] * F_DIM) + p * 2;
                            b2x = rn[0]; b2y = rn[1];
                        }
                        unsigned wds[8] = { b0x.x, b0x.y, b0x.z, b0x.w,
                                            b0y.x, b0y.y, b0y.z, b0y.w };
                        #pragma unroll
                        for (int dw = 0; dw < 8; ++dw) {
                            #pragma unroll
                            for (int k = 0; k < 4; ++k)
                                acci[dw * 4 + k] += sbyte(wds[dw], k);
                        }
                        b0x = b1x; b0y = b1y;
                        b1x = b2x; b1y = b2y;
                    }
                }
            }
            #pragma unroll
            for (int q = 0; q < 4; ++q) {
                short8v nb;
                #pragma unroll
                for (int e = 0; e < 8; ++e)
                    nb[e] = bf16bits((float)acci[q * 8 + e] * 0.0625f);
                *(short8v*)(basep + q * 8) = nb;
            }
        }
        __syncthreads();

        const int w  = tid >> 6;
        const int l  = tid & 63;
        const int cg = l & 15;
        const int rg = l >> 4;

        short8v a[8];
        const short* arow = &As[(w * 16 + cg) * LDSN + rg * 8];
        #pragma unroll
        for (int s = 0; s < 4; ++s) a[s] = *(const short8v*)(arow + s * 32);
        int srow = d * PER_DEG + rows0 + w * 16 + cg;
        if (srow >= N_ATOMS) srow = N_ATOMS - 1;
        {
            const unsigned char* sp8 = ai8 + (size_t)srow * F_DIM + rg * 8;
            #pragma unroll
            for (int s = 0; s < 4; ++s) {
                uint2 u = *(const uint2*)(sp8 + s * 32);
                short8v sv;
                #pragma unroll
                for (int e = 0; e < 8; ++e) {
                    unsigned wd = (e < 4) ? u.x : u.y;
                    sv[e] = bf16bits((float)sbyte(wd, e & 3) * 0.0625f);
                }
                a[4 + s] = sv;
            }
        }

        const short* wtd = wt + (size_t)d * F_DIM * WT_K;
        f32x4 aA[8];
        #pragma unroll
        for (int n = 0; n < 8; ++n) aA[n] = 0.0f;
        #pragma unroll
        for (int s = 0; s < 8; ++s) {
            #pragma unroll
            for (int n = 0; n < 8; ++n) {
                short8v bv = *(const short8v*)(wtd + (n * 16 + cg) * WT_K + s * 32 + rg * 8);
                aA[n] = __builtin_amdgcn_mfma_f32_16x16x32_bf16(a[s], bv, aA[n], 0, 0, 0);
            }
        }

        float biasv[8], gam[8], bet[8];
        #pragma unroll
        for (int n = 0; n < 8; ++n) {
            int col = n * 16 + cg;
            biasv[n] = (d > 0) ? (b[(2 * d - 2) * F_DIM + col] + b[(2 * d - 1) * F_DIM + col])
                               : b[20 * F_DIM + col];
            gam[n] = gamma[col];
            bet[n] = beta[col];
        }
        const int valid = (PER_DEG - rows0 < BM) ? (PER_DEG - rows0) : BM;
        #pragma unroll
        for (int j = 0; j < 4; ++j) {
            const int rl = w * 16 + rg * 4 + j;
            float x[8];
            float s1 = 0.f, s2 = 0.f;
            #pragma unroll
            for (int n = 0; n < 8; ++n) {
                x[n] = aA[n][j] + biasv[n];
                s1 += x[n];
                s2 += x[n] * x[n];
            }
            #pragma unroll
            for (int m = 1; m < 16; m <<= 1) {
                s1 += __shfl_xor(s1, m);
                s2 += __shfl_xor(s2, m);
            }
            float mean = s1 * (1.0f / 128.0f);
            float var  = fmaxf(s2 * (1.0f / 128.0f) - mean * mean, 0.0f);
            float inv  = 1.0f / (sqrtf(var + 1e-5f) + 1e-5f);
            if (rl < valid) {
                float* op = outN + (size_t)(d * PER_DEG + rows0 + rl) * F_DIM;
                #pragma unroll
                for (int n = 0; n < 8; ++n)
                    op[n * 16 + cg] = gam[n] * ((x[n] - mean) * inv) + bet[n];
            }
        }
    } else {
        // ================= mol-reduce block (2 keys) =================
        const int mb   = bid - i0;            // mol block index
        const int key  = mb * 2 + (tid >> 7); // m * NDEG + d
        const int c    = tid & 127;
        if (key < BATCH * NDEG) {
            const int m    = key / NDEG;
            const int dd   = key - m * NDEG;
            const int base = off[key];
            const int n    = hist2[key];
            float acc = 0.0f;
            if (n > 0) {
                int id0 = idx[base];
                float vcur = atoms[(size_t)id0 * F_DIM + c];
                for (int t = 0; t < n; ++t) {
                    float vnext = 0.0f;
                    if (t + 1 < n) {
                        int id1 = idx[base + t + 1];
                        vnext = atoms[(size_t)id1 * F_DIM + c];
                    }
                    acc += vcur;
                    vcur = vnext;
                }
            }
            short* out = sums + (size_t)m * GWT_K;
            out[dd * F_DIM + c] = bf16bits(acc);
            if (c == 0) out[1408 + dd] = bf16bits((float)n);
            if (dd == 0 && c >= 11 && c < 32) out[1408 + c] = 0;
        }
    }
}

// ---------- gat GEMM: outG[4096][128] = sums[4096][1440] @ gwt^T -----------
__global__ __launch_bounds__(256) void gat_gemm(
    const short* __restrict__ sums, const short* __restrict__ gwt,
    float* __restrict__ outG)
{
    const int rows0 = blockIdx.x * 64;
    const int tid = threadIdx.x;
    const int w = tid >> 6, l = tid & 63, cg = l & 15, rg = l >> 4;
    const short* ap = sums + (size_t)(rows0 + w * 16 + cg) * GWT_K + rg * 8;
    f32x4 acc[8];
    #pragma unroll
    for (int n = 0; n < 8; ++n) acc[n] = 0.0f;
    for (int ks = 0; ks < GWT_K / 32; ++ks) {
        short8v av = *(const short8v*)(ap + ks * 32);
        #pragma unroll
        for (int n = 0; n < 8; ++n) {
            short8v bv = *(const short8v*)(gwt + (size_t)(n * 16 + cg) * GWT_K + ks * 32 + rg * 8);
            acc[n] = __builtin_amdgcn_mfma_f32_16x16x32_bf16(av, bv, acc[n], 0, 0, 0);
        }
    }
    #pragma unroll
    for (int j = 0; j < 4; ++j) {
        int r = rows0 + w * 16 + rg * 4 + j;
        #pragma unroll
        for (int n = 0; n < 8; ++n)
            outG[(size_t)r * F_DIM + n * 16 + cg] = acc[n][j];
    }
}

// =================== legacy fallback (R1 kernel) ===========================
__global__ void prep_wt_full(const float* __restrict__ W, const float* __restrict__ gW,
                             short* __restrict__ wt) {
    int idx = blockIdx.x * blockDim.x + threadIdx.x;
    const int total = NDEG * F_DIM * WT_K_L;
    if (idx >= total) return;
    int d   = idx / (F_DIM * WT_K_L);
    int rem = idx % (F_DIM * WT_K_L);
    int c   = rem / WT_K_L;
    int k   = rem % WT_K_L;
    float v;
    if (k < 256) {
        if (d == 0) v = (k < 128) ? 0.0f : W[20 * 16384 + (k - 128) * F_DIM + c];
        else {
            int wi = (k < 128) ? (2 * (d - 1)) : (2 * (d - 1) + 1);
            v = W[wi * 16384 + (k & 127) * F_DIM + c];
        }
    } else {
        int gi = (d == 0) ? 10 : (d - 1);
        v = gW[gi * 16384 + (k - 256) * F_DIM + c];
    }
    wt[idx] = bf16bits(v);
}

__global__ __launch_bounds__(256, 2) void fused_legacy(
    const float* __restrict__ atoms,
    const int* __restrict__ membership, AdjPtrs adj,
    const short* __restrict__ wt, const float* __restrict__ b,
    const float* __restrict__ gb, const float* __restrict__ gamma,
    const float* __restrict__ beta, float* __restrict__ outN, float* __restrict__ outG)
{
    __shared__ short As[BM * LDST_L];
    const int bid = blockIdx.x, d = bid / BPD, rb = bid % BPD;
    const int rows0 = rb * BM, tid = threadIdx.x;
    {
        const int rloc = tid >> 2, p = tid & 3;
        const int grow = rows0 + rloc;
        const bool rv = grow < PER_DEG;
        short* basep = &As[rloc * LDST_L + p * 32];
        f32x4 accn[8], selfv[8];
        #pragma unroll
        for (int q = 0; q < 8; ++q) { accn[q] = 0.0f; selfv[q] = 0.0f; }
        const f32x4* atomsv = (const f32x4*)atoms;
        if (rv) {
            if (d > 0) {
                const int* ar = adj.p[d - 1] + (size_t)grow * d;
                int idxs[MAXD];
                #pragma unroll
                for (int j = 0; j < MAXD; ++j) idxs[j] = (j < d) ? ar[j] : 0;
                #pragma unroll
                for (int j = 0; j < MAXD; ++j) if (j < d) {
                    const f32x4* s = atomsv + (size_t)idxs[j] * 32 + p * 8;
                    #pragma unroll
                    for (int q = 0; q < 8; ++q) accn[q] += s[q];
                }
            }
            const f32x4* s = atomsv + (size_t)(d * PER_DEG + grow) * 32 + p * 8;
            #pragma unroll
            for (int q = 0; q < 8; ++q) selfv[q] = s[q];
        }
        #pragma unroll
        for (int q = 0; q < 8; ++q) {
            short4v nb = { bf16bits(accn[q][0]), bf16bits(accn[q][1]),
                           bf16bits(accn[q][2]), bf16bits(accn[q][3]) };
            short4v sv = { bf16bits(selfv[q][0]), bf16bits(selfv[q][1]),
                           bf16bits(selfv[q][2]), bf16bits(selfv[q][3]) };
            *(short4v*)(basep + q * 4) = nb;
            *(short4v*)(basep + 128 + q * 4) = sv;
        }
    }
    __syncthreads();
    const int w = tid >> 6, l = tid & 63, cg = l & 15, rg = l >> 4;
    short8v a[8];
    const short* arow = &As[(w * 16 + cg) * LDST_L + rg * 8];
    #pragma unroll
    for (int s = 0; s < 8; ++s) a[s] = *(const short8v*)(arow + s * 32);
    const short* wtd = wt + (size_t)d * F_DIM * WT_K_L;
    f32x4 aA[8], aG[8];
    #pragma unroll
    for (int n = 0; n < 8; ++n) { aA[n] = 0.0f; aG[n] = 0.0f; }
    #pragma unroll
    for (int s = 0; s < 8; ++s) {
        #pragma unroll
        for (int n = 0; n < 8; ++n) {
            short8v bv = *(const short8v*)(wtd + (n * 16 + cg) * WT_K_L + s * 32 + rg * 8);
            aA[n] = __builtin_amdgcn_mfma_f32_16x16x32_bf16(a[s], bv, aA[n], 0, 0, 0);
        }
    }
    #pragma unroll
    for (int s = 0; s < 4; ++s) {
        #pragma unroll
        for (int n = 0; n < 8; ++n) {
            short8v bv = *(const short8v*)(wtd + (n * 16 + cg) * WT_K_L + 256 + s * 32 + rg * 8);
            aG[n] = __builtin_amdgcn_mfma_f32_16x16x32_bf16(a[4 + s], bv, aG[n], 0, 0, 0);
        }
    }
    const int gi = (d == 0) ? 10 : (d - 1);
    float biasv[8], gbv[8], gam[8], bet[8];
    #pragma unroll
    for (int n = 0; n < 8; ++n) {
        int col = n * 16 + cg;
        biasv[n] = (d > 0) ? (b[(2*d-2)*F_DIM+col] + b[(2*d-1)*F_DIM+col]) : b[20*F_DIM+col];
        gbv[n] = gb[gi * F_DIM + col];
        gam[n] = gamma[col]; bet[n] = beta[col];
    }
    const int valid = (PER_DEG - rows0 < BM) ? (PER_DEG - rows0) : BM;
    #pragma unroll
    for (int j = 0; j < 4; ++j) {
        const int rl = w * 16 + rg * 4 + j;
        float x[8], s1 = 0.f, s2 = 0.f;
        #pragma unroll
        for (int n = 0; n < 8; ++n) { x[n] = aA[n][j] + biasv[n]; s1 += x[n]; s2 += x[n]*x[n]; }
        #pragma unroll
        for (int m = 1; m < 16; m <<= 1) { s1 += __shfl_xor(s1, m); s2 += __shfl_xor(s2, m); }
        float mean = s1 * (1.0f/128.0f);
        float var  = fmaxf(s2 * (1.0f/128.0f) - mean*mean, 0.0f);
        float inv  = 1.0f / (sqrtf(var + 1e-5f) + 1e-5f);
        if (rl < valid) {
            const int growi = d * PER_DEG + rows0 + rl;
            float* op = outN + (size_t)growi * F_DIM;
            float* gp = outG + (size_t)membership[growi] * F_DIM;
            #pragma unroll
            for (int n = 0; n < 8; ++n) {
                int col = n * 16 + cg;
                op[col] = gam[n] * ((x[n] - mean) * inv) + bet[n];
                atomicAdd(&gp[col], aG[n][j] + gbv[n]);
            }
        }
    }
}

// ===========================================================================
extern "C" void kernel_launch(void* const* d_in, const int* in_sizes, int n_in,
                              void* d_out, int out_size, void* d_ws, size_t ws_size,
                              hipStream_t stream) {
    const float* atoms      = (const float*)d_in[0];
    const int*   membership = (const int*)d_in[2];
    AdjPtrs adj;
    for (int i = 0; i < MAXD; ++i) adj.p[i] = (const int*)d_in[3 + i];
    const float* W     = (const float*)d_in[13];
    const float* b     = (const float*)d_in[14];
    const float* gW    = (const float*)d_in[15];
    const float* gb    = (const float*)d_in[16];
    const float* gamma = (const float*)d_in[17];
    const float* beta  = (const float*)d_in[18];

    float* outN = (float*)d_out;
    float* outG = outN + (size_t)N_ATOMS * F_DIM;

    auto al = [](size_t x) { return (x + 255) & ~(size_t)255; };
    const size_t sz_wt   = al((size_t)NDEG * F_DIM * WT_K * 2);    // 720 KB
    const size_t sz_gwt  = al((size_t)F_DIM * GWT_K * 2);          // 360 KB
    const size_t sz_h    = al((size_t)BATCH * NDEG * 4);           // 180 KB
    const size_t sz_idx  = al((size_t)N_ATOMS * 4);                // 2.2 MB
    const size_t sz_sums = al((size_t)BATCH * GWT_K * 2);          // 11.8 MB
    const size_t sz_ai8  = (size_t)N_ATOMS * F_DIM;                // 70.4 MB

    size_t o = 0;
    short* wt    = (short*)((char*)d_ws + o); o += sz_wt;
    short* gwt   = (short*)((char*)d_ws + o); o += sz_gwt;
    int*   hist2 = (int*)  ((char*)d_ws + o); o += sz_h;
    int*   offa  = (int*)  ((char*)d_ws + o); o += sz_h;
    int*   cura  = (int*)  ((char*)d_ws + o); o += sz_h;
    int*   idx   = (int*)  ((char*)d_ws + o); o += sz_idx;
    short* sums  = (short*)((char*)d_ws + o); o += sz_sums;
    unsigned char* ai8 = (unsigned char*)((char*)d_ws + o); o += sz_ai8;

    if (ws_size >= o) {
        prep_wt_main<<<(NDEG * F_DIM * WT_K + 255) / 256, 256, 0, stream>>>(W, wt);
        prep_gwt<<<(F_DIM * GWT_K + 255) / 256, 256, 0, stream>>>(gW, gb, gwt);
        hipMemsetAsync(hist2, 0, (size_t)BATCH * NDEG * 4, stream);
        to_i8<<<2048, 256, 0, stream>>>(atoms, ai8);
        hist_kernel<<<(N_ATOMS + 255) / 256, 256, 0, stream>>>(membership, hist2);
        scan_offsets<<<1, 1024, 0, stream>>>(hist2, offa, cura);
        scatter_kernel<<<(N_ATOMS + 255) / 256, 256, 0, stream>>>(membership, cura, idx);
        fused_all<<<ALL_BLKS, 256, 0, stream>>>(ai8, atoms, adj, wt, b, gamma, beta,
                                                idx, offa, hist2, outN, sums);
        gat_gemm<<<BATCH / 64, 256, 0, stream>>>(sums, gwt, outG);
    } else {
        // ---- legacy fallback (atomics path, f32 reads) ----
        short* lwt = (short*)d_ws;
        prep_wt_full<<<(NDEG * F_DIM * WT_K_L + 255) / 256, 256, 0, stream>>>(W, gW, lwt);
        hipMemsetAsync(outG, 0, (size_t)BATCH * F_DIM * 4, stream);
        fused_legacy<<<NDEG * BPD, 256, 0, stream>>>(atoms, membership, adj, lwt,
                                                     b, gb, gamma, beta, outN, outG);
    }
}

// Round 13
// 655.354 us; speedup vs baseline: 1.1016x; 1.1016x over previous
//
#include <hip/hip_runtime.h>
#include <hip/hip_bf16.h>

// Problem constants (fixed by setup_inputs)
#define F_DIM   128
#define PER_DEG 50000
#define NDEG    11
#define MAXD    10
#define BATCH   4096
#define N_ATOMS (PER_DEG * NDEG)

// Tile config
#define BM     64
#define LDSN   136                       // 128 + 8 pad shorts (nbr half only)
#define BPD    ((PER_DEG + BM - 1) / BM) // 782 blocks per degree
#define WT_K   256                       // main kernel: [Wnbr;Wself]
#define GWT_K  1440                      // gat GEMM: 11*128 feats + 11 counts + pad
#define LDST_L 264                       // legacy fallback stride
#define WT_K_L 384                       // legacy fallback wt K

typedef __attribute__((ext_vector_type(4))) float f32x4;
typedef __attribute__((ext_vector_type(8))) short short8v;
typedef __attribute__((ext_vector_type(4))) short short4v;

struct AdjPtrs { const int* p[MAXD]; };

__device__ inline short bf16bits(float x) {
    __hip_bfloat16 h = __float2bfloat16(x);
    return __builtin_bit_cast(short, h);
}
__device__ inline float bf_lo(unsigned u) { return __builtin_bit_cast(float, u << 16); }
__device__ inline float bf_hi(unsigned u) { return __builtin_bit_cast(float, u & 0xFFFF0000u); }
__device__ inline float bf2f(short s) {
    return __builtin_bit_cast(float, ((unsigned)(unsigned short)s) << 16);
}

// ---------- weight prep: wt[d][c][k], k in [0,256) = [Wnbr;Wself] ----------
__global__ void prep_wt_main(const float* __restrict__ W, short* __restrict__ wt) {
    int idx = blockIdx.x * blockDim.x + threadIdx.x;
    const int total = NDEG * F_DIM * WT_K;
    if (idx >= total) return;
    int d   = idx / (F_DIM * WT_K);
    int rem = idx % (F_DIM * WT_K);
    int c   = rem / WT_K;
    int k   = rem % WT_K;
    float v;
    if (d == 0) {
        v = (k < 128) ? 0.0f : W[20 * 16384 + (k - 128) * F_DIM + c];
    } else {
        int wi = (k < 128) ? (2 * (d - 1)) : (2 * (d - 1) + 1);
        v = W[wi * 16384 + (k & 127) * F_DIM + c];
    }
    wt[idx] = bf16bits(v);
}

// ---------- gat GEMM weights: gwt[c][k], K=1440 (feats | gb-row | zeros) ----
__global__ void prep_gwt(const float* __restrict__ gW, const float* __restrict__ gb,
                         short* __restrict__ gwt) {
    int idx = blockIdx.x * blockDim.x + threadIdx.x;
    const int total = F_DIM * GWT_K;
    if (idx >= total) return;
    int c = idx / GWT_K;
    int k = idx % GWT_K;
    float v = 0.0f;
    if (k < 1408) {
        int dd = k >> 7, f = k & 127;
        int gi = dd ? (dd - 1) : 10;
        v = gW[gi * 16384 + f * F_DIM + c];
    } else if (k < 1419) {
        int dd = k - 1408;
        int gi = dd ? (dd - 1) : 10;
        v = gb[gi * F_DIM + c];
    }
    gwt[idx] = bf16bits(v);
}

// ---------- one-time atoms f32 -> bf16 table (140.8 MB; cheapest aux: R5) --
__global__ void to_bf16(const float* __restrict__ in, short* __restrict__ out) {
    const size_t n8 = (size_t)N_ATOMS * F_DIM / 8;
    size_t stride = (size_t)gridDim.x * blockDim.x;
    for (size_t k = (size_t)blockIdx.x * blockDim.x + threadIdx.x; k < n8; k += stride) {
        f32x4 a = __builtin_nontemporal_load((const f32x4*)in + 2 * k);
        f32x4 c = __builtin_nontemporal_load((const f32x4*)in + 2 * k + 1);
        short8v o = { bf16bits(a[0]), bf16bits(a[1]), bf16bits(a[2]), bf16bits(a[3]),
                      bf16bits(c[0]), bf16bits(c[1]), bf16bits(c[2]), bf16bits(c[3]) };
        ((short8v*)out)[k] = o;
    }
}

// ---------- inverted index over (molecule, degree) keys --------------------
__global__ void hist_kernel(const int* __restrict__ mem, int* __restrict__ hist2) {
    int i = blockIdx.x * blockDim.x + threadIdx.x;
    if (i >= N_ATOMS) return;
    atomicAdd(&hist2[mem[i] * NDEG + i / PER_DEG], 1);
}

__global__ void scan_offsets(const int* __restrict__ hist2,
                             int* __restrict__ off, int* __restrict__ cur) {
    __shared__ int lds[1024];
    const int tid = threadIdx.x;
    int h[4][NDEG];
    int tsum = 0;
    #pragma unroll
    for (int mi = 0; mi < 4; ++mi) {
        int m = tid * 4 + mi;
        #pragma unroll
        for (int dd = 0; dd < NDEG; ++dd) { h[mi][dd] = hist2[m * NDEG + dd]; tsum += h[mi][dd]; }
    }
    lds[tid] = tsum;
    __syncthreads();
    for (int ofs = 1; ofs < 1024; ofs <<= 1) {
        int v = (tid >= ofs) ? lds[tid - ofs] : 0;
        __syncthreads();
        lds[tid] += v;
        __syncthreads();
    }
    int run = lds[tid] - tsum;   // exclusive prefix
    #pragma unroll
    for (int mi = 0; mi < 4; ++mi) {
        int m = tid * 4 + mi;
        #pragma unroll
        for (int dd = 0; dd < NDEG; ++dd) {
            int k = m * NDEG + dd;
            off[k] = run; cur[k] = run;
            run += h[mi][dd];
        }
    }
}

__global__ void scatter_kernel(const int* __restrict__ mem,
                               int* __restrict__ cur, int* __restrict__ idx) {
    int i = blockIdx.x * blockDim.x + threadIdx.x;
    if (i >= N_ATOMS) return;
    int pos = atomicAdd(&cur[mem[i] * NDEG + i / PER_DEG], 1);
    idx[pos] = i;
}

// ---------- main fused kernel: gather -> [nbr|self]@Wcat -> LN -> outN -----
// Best-known assembly (R12): bf16 table (int8 bought 0 time: R7) + depth-2
// software pipeline + degree-interleaved block map (R9's fused gain) +
// 4 blocks/CU (R8: 6 worse) + plain stores (R6: nt-staging no help).
// 128 B in flight/thread — 20x below R3's flood that caused WRITE blowup.
__global__ __launch_bounds__(256, 4) void fused_deg(
    const short* __restrict__ abf,
    AdjPtrs adj,
    const short* __restrict__ wt,
    const float* __restrict__ b,
    const float* __restrict__ gamma,
    const float* __restrict__ beta,
    float* __restrict__ outN)
{
    __shared__ short As[BM * LDSN];
    const int bid   = blockIdx.x;
    const int d     = bid % NDEG;        // degree-interleaved dispatch
    const int rb    = bid / NDEG;
    const int rows0 = rb * BM;
    const int tid   = threadIdx.x;

    // gather phase: 4 threads/row, 32 features each, nbr sum only
    {
        const int rloc = tid >> 2;
        const int p    = tid & 3;
        const int grow = rows0 + rloc;
        short* basep = &As[rloc * LDSN + p * 32];
        float acc[32];
        #pragma unroll
        for (int e = 0; e < 32; ++e) acc[e] = 0.0f;
        if (grow < PER_DEG && d > 0) {
            const int* ar = adj.p[d - 1] + (size_t)grow * d;
            int idxs[MAXD];
            #pragma unroll
            for (int j = 0; j < MAXD; ++j) idxs[j] = (j < d) ? ar[j] : 0;
            // depth-2 pipeline: ref j+1's 64 B in flight while ref j accumulates
            uint4 c0, c1, c2, c3;
            {
                const uint4* r0 = (const uint4*)(abf + (size_t)idxs[0] * F_DIM) + p * 4;
                c0 = r0[0]; c1 = r0[1]; c2 = r0[2]; c3 = r0[3];
            }
            #pragma unroll
            for (int j = 0; j < MAXD; ++j) {
                if (j < d) {
                    uint4 n0 = c0, n1 = c1, n2 = c2, n3 = c3;
                    if (j + 1 < d) {
                        const uint4* rn =
                            (const uint4*)(abf + (size_t)idxs[j + 1] * F_DIM) + p * 4;
                        n0 = rn[0]; n1 = rn[1]; n2 = rn[2]; n3 = rn[3];
                    }
                    uint4 ws[4] = { c0, c1, c2, c3 };
                    #pragma unroll
                    for (int q = 0; q < 4; ++q) {
                        uint4 u = ws[q];
                        acc[q * 8 + 0] += bf_lo(u.x); acc[q * 8 + 1] += bf_hi(u.x);
                        acc[q * 8 + 2] += bf_lo(u.y); acc[q * 8 + 3] += bf_hi(u.y);
                        acc[q * 8 + 4] += bf_lo(u.z); acc[q * 8 + 5] += bf_hi(u.z);
                        acc[q * 8 + 6] += bf_lo(u.w); acc[q * 8 + 7] += bf_hi(u.w);
                    }
                    c0 = n0; c1 = n1; c2 = n2; c3 = n3;
                }
            }
        }
        #pragma unroll
        for (int q = 0; q < 4; ++q) {
            short8v nb = { bf16bits(acc[q * 8 + 0]), bf16bits(acc[q * 8 + 1]),
                           bf16bits(acc[q * 8 + 2]), bf16bits(acc[q * 8 + 3]),
                           bf16bits(acc[q * 8 + 4]), bf16bits(acc[q * 8 + 5]),
                           bf16bits(acc[q * 8 + 6]), bf16bits(acc[q * 8 + 7]) };
            *(short8v*)(basep + q * 8) = nb;
        }
    }
    __syncthreads();

    // MFMA phase: wave w owns rows w*16..w*16+15
    const int w  = tid >> 6;
    const int l  = tid & 63;
    const int cg = l & 15;
    const int rg = l >> 4;

    short8v a[8];
    const short* arow = &As[(w * 16 + cg) * LDSN + rg * 8];
    #pragma unroll
    for (int s = 0; s < 4; ++s) a[s] = *(const short8v*)(arow + s * 32);
    int srow = d * PER_DEG + rows0 + w * 16 + cg;
    if (srow >= N_ATOMS) srow = N_ATOMS - 1;
    const short* sp = abf + (size_t)srow * F_DIM + rg * 8;
    #pragma unroll
    for (int s = 0; s < 4; ++s) a[4 + s] = *(const short8v*)(sp + s * 32);

    const short* wtd = wt + (size_t)d * F_DIM * WT_K;
    f32x4 aA[8];
    #pragma unroll
    for (int n = 0; n < 8; ++n) aA[n] = 0.0f;
    #pragma unroll
    for (int s = 0; s < 8; ++s) {
        #pragma unroll
        for (int n = 0; n < 8; ++n) {
            short8v bv = *(const short8v*)(wtd + (n * 16 + cg) * WT_K + s * 32 + rg * 8);
            aA[n] = __builtin_amdgcn_mfma_f32_16x16x32_bf16(a[s], bv, aA[n], 0, 0, 0);
        }
    }

    // epilogue: bias + LayerNorm + plain stores (L2 merges them; R5-verified)
    float biasv[8], gam[8], bet[8];
    #pragma unroll
    for (int n = 0; n < 8; ++n) {
        int col = n * 16 + cg;
        biasv[n] = (d > 0) ? (b[(2 * d - 2) * F_DIM + col] + b[(2 * d - 1) * F_DIM + col])
                           : b[20 * F_DIM + col];
        gam[n] = gamma[col];
        bet[n] = beta[col];
    }
    const int valid = (PER_DEG - rows0 < BM) ? (PER_DEG - rows0) : BM;
    #pragma unroll
    for (int j = 0; j < 4; ++j) {
        const int rl = w * 16 + rg * 4 + j;
        float x[8];
        float s1 = 0.f, s2 = 0.f;
        #pragma unroll
        for (int n = 0; n < 8; ++n) {
            x[n] = aA[n][j] + biasv[n];
            s1 += x[n];
            s2 += x[n] * x[n];
        }
        #pragma unroll
        for (int m = 1; m < 16; m <<= 1) {
            s1 += __shfl_xor(s1, m);
            s2 += __shfl_xor(s2, m);
        }
        float mean = s1 * (1.0f / 128.0f);
        float var  = fmaxf(s2 * (1.0f / 128.0f) - mean * mean, 0.0f);
        float inv  = 1.0f / (sqrtf(var + 1e-5f) + 1e-5f);
        if (rl < valid) {
            float* op = outN + (size_t)(d * PER_DEG + rows0 + rl) * F_DIM;
            #pragma unroll
            for (int n = 0; n < 8; ++n)
                op[n * 16 + cg] = gam[n] * ((x[n] - mean) * inv) + bet[n];
        }
    }
}

// ---------- per-(molecule,degree) bucket sum (45056 blocks, bf16 table) ----
__global__ __launch_bounds__(128) void mol_reduce(
    const short* __restrict__ abf, const int* __restrict__ idx,
    const int* __restrict__ off, const int* __restrict__ hist2,
    short* __restrict__ sums)
{
    const int key = blockIdx.x;           // m * NDEG + d
    const int m   = key / NDEG;
    const int dd  = key - m * NDEG;
    const int c   = threadIdx.x;
    const int base = off[key];
    const int n    = hist2[key];
    float acc = 0.0f;
    if (n > 0) {
        int id0 = idx[base];
        float vcur = bf2f(abf[(size_t)id0 * F_DIM + c]);
        for (int t = 0; t < n; ++t) {
            float vnext = 0.0f;
            if (t + 1 < n) {
                int id1 = idx[base + t + 1];
                vnext = bf2f(abf[(size_t)id1 * F_DIM + c]);
            }
            acc += vcur;
            vcur = vnext;
        }
    }
    short* out = sums + (size_t)m * GWT_K;
    out[dd * F_DIM + c] = bf16bits(acc);
    if (c == 0) out[1408 + dd] = bf16bits((float)n);
    if (dd == 0 && c >= 11 && c < 32) out[1408 + c] = 0;
}

// ---------- gat GEMM: outG[4096][128] = sums[4096][1440] @ gwt^T -----------
__global__ __launch_bounds__(256) void gat_gemm(
    const short* __restrict__ sums, const short* __restrict__ gwt,
    float* __restrict__ outG)
{
    const int rows0 = blockIdx.x * 64;
    const int tid = threadIdx.x;
    const int w = tid >> 6, l = tid & 63, cg = l & 15, rg = l >> 4;
    const short* ap = sums + (size_t)(rows0 + w * 16 + cg) * GWT_K + rg * 8;
    f32x4 acc[8];
    #pragma unroll
    for (int n = 0; n < 8; ++n) acc[n] = 0.0f;
    for (int ks = 0; ks < GWT_K / 32; ++ks) {
        short8v av = *(const short8v*)(ap + ks * 32);
        #pragma unroll
        for (int n = 0; n < 8; ++n) {
            short8v bv = *(const short8v*)(gwt + (size_t)(n * 16 + cg) * GWT_K + ks * 32 + rg * 8);
            acc[n] = __builtin_amdgcn_mfma_f32_16x16x32_bf16(av, bv, acc[n], 0, 0, 0);
        }
    }
    #pragma unroll
    for (int j = 0; j < 4; ++j) {
        int r = rows0 + w * 16 + rg * 4 + j;
        #pragma unroll
        for (int n = 0; n < 8; ++n)
            outG[(size_t)r * F_DIM + n * 16 + cg] = acc[n][j];
    }
}

// =================== legacy fallback (R1 kernel) ===========================
__global__ void prep_wt_full(const float* __restrict__ W, const float* __restrict__ gW,
                             short* __restrict__ wt) {
    int idx = blockIdx.x * blockDim.x + threadIdx.x;
    const int total = NDEG * F_DIM * WT_K_L;
    if (idx >= total) return;
    int d   = idx / (F_DIM * WT_K_L);
    int rem = idx % (F_DIM * WT_K_L);
    int c   = rem / WT_K_L;
    int k   = rem % WT_K_L;
    float v;
    if (k < 256) {
        if (d == 0) v = (k < 128) ? 0.0f : W[20 * 16384 + (k - 128) * F_DIM + c];
        else {
            int wi = (k < 128) ? (2 * (d - 1)) : (2 * (d - 1) + 1);
            v = W[wi * 16384 + (k & 127) * F_DIM + c];
        }
    } else {
        int gi = (d == 0) ? 10 : (d - 1);
        v = gW[gi * 16384 + (k - 256) * F_DIM + c];
    }
    wt[idx] = bf16bits(v);
}

__global__ __launch_bounds__(256, 2) void fused_legacy(
    const float* __restrict__ atoms,
    const int* __restrict__ membership, AdjPtrs adj,
    const short* __restrict__ wt, const float* __restrict__ b,
    const float* __restrict__ gb, const float* __restrict__ gamma,
    const float* __restrict__ beta, float* __restrict__ outN, float* __restrict__ outG)
{
    __shared__ short As[BM * LDST_L];
    const int bid = blockIdx.x, d = bid / BPD, rb = bid % BPD;
    const int rows0 = rb * BM, tid = threadIdx.x;
    {
        const int rloc = tid >> 2, p = tid & 3;
        const int grow = rows0 + rloc;
        const bool rv = grow < PER_DEG;
        short* basep = &As[rloc * LDST_L + p * 32];
        f32x4 accn[8], selfv[8];
        #pragma unroll
        for (int q = 0; q < 8; ++q) { accn[q] = 0.0f; selfv[q] = 0.0f; }
        const f32x4* atomsv = (const f32x4*)atoms;
        if (rv) {
            if (d > 0) {
                const int* ar = adj.p[d - 1] + (size_t)grow * d;
                int idxs[MAXD];
                #pragma unroll
                for (int j = 0; j < MAXD; ++j) idxs[j] = (j < d) ? ar[j] : 0;
                #pragma unroll
                for (int j = 0; j < MAXD; ++j) if (j < d) {
                    const f32x4* s = atomsv + (size_t)idxs[j] * 32 + p * 8;
                    #pragma unroll
                    for (int q = 0; q < 8; ++q) accn[q] += s[q];
                }
            }
            const f32x4* s = atomsv + (size_t)(d * PER_DEG + grow) * 32 + p * 8;
            #pragma unroll
            for (int q = 0; q < 8; ++q) selfv[q] = s[q];
        }
        #pragma unroll
        for (int q = 0; q < 8; ++q) {
            short4v nb = { bf16bits(accn[q][0]), bf16bits(accn[q][1]),
                           bf16bits(accn[q][2]), bf16bits(accn[q][3]) };
            short4v sv = { bf16bits(selfv[q][0]), bf16bits(selfv[q][1]),
                           bf16bits(selfv[q][2]), bf16bits(selfv[q][3]) };
            *(short4v*)(basep + q * 4) = nb;
            *(short4v*)(basep + 128 + q * 4) = sv;
        }
    }
    __syncthreads();
    const int w = tid >> 6, l = tid & 63, cg = l & 15, rg = l >> 4;
    short8v a[8];
    const short* arow = &As[(w * 16 + cg) * LDST_L + rg * 8];
    #pragma unroll
    for (int s = 0; s < 8; ++s) a[s] = *(const short8v*)(arow + s * 32);
    const short* wtd = wt + (size_t)d * F_DIM * WT_K_L;
    f32x4 aA[8], aG[8];
    #pragma unroll
    for (int n = 0; n < 8; ++n) { aA[n] = 0.0f; aG[n] = 0.0f; }
    #pragma unroll
    for (int s = 0; s < 8; ++s) {
        #pragma unroll
        for (int n = 0; n < 8; ++n) {
            short8v bv = *(const short8v*)(wtd + (n * 16 + cg) * WT_K_L + s * 32 + rg * 8);
            aA[n] = __builtin_amdgcn_mfma_f32_16x16x32_bf16(a[s], bv, aA[n], 0, 0, 0);
        }
    }
    #pragma unroll
    for (int s = 0; s < 4; ++s) {
        #pragma unroll
        for (int n = 0; n < 8; ++n) {
            short8v bv = *(const short8v*)(wtd + (n * 16 + cg) * WT_K_L + 256 + s * 32 + rg * 8);
            aG[n] = __builtin_amdgcn_mfma_f32_16x16x32_bf16(a[4 + s], bv, aG[n], 0, 0, 0);
        }
    }
    const int gi = (d == 0) ? 10 : (d - 1);
    float biasv[8], gbv[8], gam[8], bet[8];
    #pragma unroll
    for (int n = 0; n < 8; ++n) {
        int col = n * 16 + cg;
        biasv[n] = (d > 0) ? (b[(2*d-2)*F_DIM+col] + b[(2*d-1)*F_DIM+col]) : b[20*F_DIM+col];
        gbv[n] = gb[gi * F_DIM + col];
        gam[n] = gamma[col]; bet[n] = beta[col];
    }
    const int valid = (PER_DEG - rows0 < BM) ? (PER_DEG - rows0) : BM;
    #pragma unroll
    for (int j = 0; j < 4; ++j) {
        const int rl = w * 16 + rg * 4 + j;
        float x[8], s1 = 0.f, s2 = 0.f;
        #pragma unroll
        for (int n = 0; n < 8; ++n) { x[n] = aA[n][j] + biasv[n]; s1 += x[n]; s2 += x[n]*x[n]; }
        #pragma unroll
        for (int m = 1; m < 16; m <<= 1) { s1 += __shfl_xor(s1, m); s2 += __shfl_xor(s2, m); }
        float mean = s1 * (1.0f/128.0f);
        float var  = fmaxf(s2 * (1.0f/128.0f) - mean*mean, 0.0f);
        float inv  = 1.0f / (sqrtf(var + 1e-5f) + 1e-5f);
        if (rl < valid) {
            const int growi = d * PER_DEG + rows0 + rl;
            float* op = outN + (size_t)growi * F_DIM;
            float* gp = outG + (size_t)membership[growi] * F_DIM;
            #pragma unroll
            for (int n = 0; n < 8; ++n) {
                int col = n * 16 + cg;
                op[col] = gam[n] * ((x[n] - mean) * inv) + bet[n];
                atomicAdd(&gp[col], aG[n][j] + gbv[n]);
            }
        }
    }
}

// ===========================================================================
extern "C" void kernel_launch(void* const* d_in, const int* in_sizes, int n_in,
                              void* d_out, int out_size, void* d_ws, size_t ws_size,
                              hipStream_t stream) {
    const float* atoms      = (const float*)d_in[0];
    const int*   membership = (const int*)d_in[2];
    AdjPtrs adj;
    for (int i = 0; i < MAXD; ++i) adj.p[i] = (const int*)d_in[3 + i];
    const float* W     = (const float*)d_in[13];
    const float* b     = (const float*)d_in[14];
    const float* gW    = (const float*)d_in[15];
    const float* gb    = (const float*)d_in[16];
    const float* gamma = (const float*)d_in[17];
    const float* beta  = (const float*)d_in[18];

    float* outN = (float*)d_out;
    float* outG = outN + (size_t)N_ATOMS * F_DIM;

    auto al = [](size_t x) { return (x + 255) & ~(size_t)255; };
    const size_t sz_wt   = al((size_t)NDEG * F_DIM * WT_K * 2);    // 720 KB
    const size_t sz_gwt  = al((size_t)F_DIM * GWT_K * 2);          // 360 KB
    const size_t sz_h    = al((size_t)BATCH * NDEG * 4);           // 180 KB
    const size_t sz_idx  = al((size_t)N_ATOMS * 4);                // 2.2 MB
    const size_t sz_sums = al((size_t)BATCH * GWT_K * 2);          // 11.8 MB
    const size_t sz_abf  = (size_t)N_ATOMS * F_DIM * 2;            // 140.8 MB

    size_t o = 0;
    short* wt    = (short*)((char*)d_ws + o); o += sz_wt;
    short* gwt   = (short*)((char*)d_ws + o); o += sz_gwt;
    int*   hist2 = (int*)  ((char*)d_ws + o); o += sz_h;
    int*   offa  = (int*)  ((char*)d_ws + o); o += sz_h;
    int*   cura  = (int*)  ((char*)d_ws + o); o += sz_h;
    int*   idx   = (int*)  ((char*)d_ws + o); o += sz_idx;
    short* sums  = (short*)((char*)d_ws + o); o += sz_sums;
    short* abf   = (short*)((char*)d_ws + o); o += sz_abf;

    if (ws_size >= o) {
        prep_wt_main<<<(NDEG * F_DIM * WT_K + 255) / 256, 256, 0, stream>>>(W, wt);
        prep_gwt<<<(F_DIM * GWT_K + 255) / 256, 256, 0, stream>>>(gW, gb, gwt);
        hipMemsetAsync(hist2, 0, (size_t)BATCH * NDEG * 4, stream);
        to_bf16<<<2048, 256, 0, stream>>>(atoms, abf);
        hist_kernel<<<(N_ATOMS + 255) / 256, 256, 0, stream>>>(membership, hist2);
        scan_offsets<<<1, 1024, 0, stream>>>(hist2, offa, cura);
        scatter_kernel<<<(N_ATOMS + 255) / 256, 256, 0, stream>>>(membership, cura, idx);
        fused_deg<<<NDEG * BPD, 256, 0, stream>>>(abf, adj, wt, b, gamma, beta, outN);
        mol_reduce<<<BATCH * NDEG, 128, 0, stream>>>(abf, idx, offa, hist2, sums);
        gat_gemm<<<BATCH / 64, 256, 0, stream>>>(sums, gwt, outG);
    } else {
        // ---- legacy fallback (atomics path, f32 reads) ----
        short* lwt = (short*)d_ws;
        prep_wt_full<<<(NDEG * F_DIM * WT_K_L + 255) / 256, 256, 0, stream>>>(W, gW, lwt);
        hipMemsetAsync(outG, 0, (size_t)BATCH * F_DIM * 4, stream);
        fused_legacy<<<NDEG * BPD, 256, 0, stream>>>(atoms, membership, adj, lwt,
                                                     b, gb, gamma, beta, outN, outG);
    }
}

// Round 14
// 611.209 us; speedup vs baseline: 1.1811x; 1.0722x over previous
//
#include <hip/hip_runtime.h>
#include <hip/hip_bf16.h>

// Problem constants (fixed by setup_inputs)
#define F_DIM   128
#define PER_DEG 50000
#define NDEG    11
#define MAXD    10
#define BATCH   4096
#define N_ATOMS (PER_DEG * NDEG)

// Tile config
#define BM     64
#define LDSN   136                       // 128 + 8 pad shorts (nbr half only)
#define BPD    ((PER_DEG + BM - 1) / BM) // 782 blocks per degree
#define WT_K   256                       // main kernel: [Wnbr;Wself]
#define GWT_K  1440                      // gat GEMM: 11*128 feats + 11 counts + pad
#define LDST_L 264                       // legacy fallback stride
#define WT_K_L 384                       // legacy fallback wt K

typedef __attribute__((ext_vector_type(4))) float f32x4;
typedef __attribute__((ext_vector_type(8))) short short8v;
typedef __attribute__((ext_vector_type(4))) short short4v;

struct AdjPtrs { const int* p[MAXD]; };

__device__ inline short bf16bits(float x) {
    __hip_bfloat16 h = __float2bfloat16(x);
    return __builtin_bit_cast(short, h);
}
__device__ inline float bf_lo(unsigned u) { return __builtin_bit_cast(float, u << 16); }
__device__ inline float bf_hi(unsigned u) { return __builtin_bit_cast(float, u & 0xFFFF0000u); }
__device__ inline float bf2f(short s) {
    return __builtin_bit_cast(float, ((unsigned)(unsigned short)s) << 16);
}

// ---------- weight prep: wt[d][c][k], k in [0,256) = [Wnbr;Wself] ----------
__global__ void prep_wt_main(const float* __restrict__ W, short* __restrict__ wt) {
    int idx = blockIdx.x * blockDim.x + threadIdx.x;
    const int total = NDEG * F_DIM * WT_K;
    if (idx >= total) return;
    int d   = idx / (F_DIM * WT_K);
    int rem = idx % (F_DIM * WT_K);
    int c   = rem / WT_K;
    int k   = rem % WT_K;
    float v;
    if (d == 0) {
        v = (k < 128) ? 0.0f : W[20 * 16384 + (k - 128) * F_DIM + c];
    } else {
        int wi = (k < 128) ? (2 * (d - 1)) : (2 * (d - 1) + 1);
        v = W[wi * 16384 + (k & 127) * F_DIM + c];
    }
    wt[idx] = bf16bits(v);
}

// ---------- gat GEMM weights: gwt[c][k], K=1440 (feats | gb-row | zeros) ----
__global__ void prep_gwt(const float* __restrict__ gW, const float* __restrict__ gb,
                         short* __restrict__ gwt) {
    int idx = blockIdx.x * blockDim.x + threadIdx.x;
    const int total = F_DIM * GWT_K;
    if (idx >= total) return;
    int c = idx / GWT_K;
    int k = idx % GWT_K;
    float v = 0.0f;
    if (k < 1408) {
        int dd = k >> 7, f = k & 127;
        int gi = dd ? (dd - 1) : 10;
        v = gW[gi * 16384 + f * F_DIM + c];
    } else if (k < 1419) {
        int dd = k - 1408;
        int gi = dd ? (dd - 1) : 10;
        v = gb[gi * F_DIM + c];
    }
    gwt[idx] = bf16bits(v);
}

// ---------- one-time atoms f32 -> bf16 table (140.8 MB, L3-resident) -------
__global__ void to_bf16(const float* __restrict__ in, short* __restrict__ out) {
    const size_t n8 = (size_t)N_ATOMS * F_DIM / 8;
    size_t stride = (size_t)gridDim.x * blockDim.x;
    for (size_t k = (size_t)blockIdx.x * blockDim.x + threadIdx.x; k < n8; k += stride) {
        f32x4 a = __builtin_nontemporal_load((const f32x4*)in + 2 * k);
        f32x4 c = __builtin_nontemporal_load((const f32x4*)in + 2 * k + 1);
        short8v o = { bf16bits(a[0]), bf16bits(a[1]), bf16bits(a[2]), bf16bits(a[3]),
                      bf16bits(c[0]), bf16bits(c[1]), bf16bits(c[2]), bf16bits(c[3]) };
        ((short8v*)out)[k] = o;
    }
}

// ---------- inverted index over (molecule, degree) keys --------------------
__global__ void hist_kernel(const int* __restrict__ mem, int* __restrict__ hist2) {
    int i = blockIdx.x * blockDim.x + threadIdx.x;
    if (i >= N_ATOMS) return;
    atomicAdd(&hist2[mem[i] * NDEG + i / PER_DEG], 1);
}

__global__ void scan_offsets(const int* __restrict__ hist2,
                             int* __restrict__ off, int* __restrict__ cur) {
    __shared__ int lds[1024];
    const int tid = threadIdx.x;
    int h[4][NDEG];
    int tsum = 0;
    #pragma unroll
    for (int mi = 0; mi < 4; ++mi) {
        int m = tid * 4 + mi;
        #pragma unroll
        for (int dd = 0; dd < NDEG; ++dd) { h[mi][dd] = hist2[m * NDEG + dd]; tsum += h[mi][dd]; }
    }
    lds[tid] = tsum;
    __syncthreads();
    for (int ofs = 1; ofs < 1024; ofs <<= 1) {
        int v = (tid >= ofs) ? lds[tid - ofs] : 0;
        __syncthreads();
        lds[tid] += v;
        __syncthreads();
    }
    int run = lds[tid] - tsum;   // exclusive prefix
    #pragma unroll
    for (int mi = 0; mi < 4; ++mi) {
        int m = tid * 4 + mi;
        #pragma unroll
        for (int dd = 0; dd < NDEG; ++dd) {
            int k = m * NDEG + dd;
            off[k] = run; cur[k] = run;
            run += h[mi][dd];
        }
    }
}

__global__ void scatter_kernel(const int* __restrict__ mem,
                               int* __restrict__ cur, int* __restrict__ idx) {
    int i = blockIdx.x * blockDim.x + threadIdx.x;
    if (i >= N_ATOMS) return;
    int pos = atomicAdd(&cur[mem[i] * NDEG + i / PER_DEG], 1);
    idx[pos] = i;
}

// ---------- main fused kernel: gather -> [nbr|self]@Wcat -> LN -> outN -----
// R5/R6-verified optimum (613us total, twice measured). Runtime-masked gather
// loop, deg-major dispatch, 4 blocks/CU, plain stores, bf16 table.
// Measured dead ends: static unroll / occ 6 -> L3 thrash (R3/R4); nt or
// LDS-staged stores -> no gain (R6); int8 table -> bytes/2 but dur unchanged
// (R7); deeper pipelines help only with the int8 table and never pay for its
// prep cost (R9/R12); merged mol_reduce -> interference (R11).
__global__ __launch_bounds__(256, 4) void fused_deg(
    const short* __restrict__ abf,
    AdjPtrs adj,
    const short* __restrict__ wt,
    const float* __restrict__ b,
    const float* __restrict__ gamma,
    const float* __restrict__ beta,
    float* __restrict__ outN)
{
    __shared__ short As[BM * LDSN];
    const int bid   = blockIdx.x;
    const int d     = bid / BPD;
    const int rb    = bid % BPD;
    const int rows0 = rb * BM;
    const int tid   = threadIdx.x;

    // gather phase: 4 threads/row, 32 features each, nbr sum only
    {
        const int rloc = tid >> 2;
        const int p    = tid & 3;
        const int grow = rows0 + rloc;
        float acc[32];
        #pragma unroll
        for (int e = 0; e < 32; ++e) acc[e] = 0.0f;
        if (grow < PER_DEG && d > 0) {
            const int* ar = adj.p[d - 1] + (size_t)grow * d;
            int idxs[MAXD];
            #pragma unroll
            for (int j = 0; j < MAXD; ++j) idxs[j] = (j < d) ? ar[j] : 0;
            #pragma unroll
            for (int j = 0; j < MAXD; ++j) {
                if (j < d) {
                    const uint4* s = (const uint4*)(abf + (size_t)idxs[j] * F_DIM) + p * 4;
                    #pragma unroll
                    for (int q = 0; q < 4; ++q) {
                        uint4 u = s[q];
                        acc[q * 8 + 0] += bf_lo(u.x); acc[q * 8 + 1] += bf_hi(u.x);
                        acc[q * 8 + 2] += bf_lo(u.y); acc[q * 8 + 3] += bf_hi(u.y);
                        acc[q * 8 + 4] += bf_lo(u.z); acc[q * 8 + 5] += bf_hi(u.z);
                        acc[q * 8 + 6] += bf_lo(u.w); acc[q * 8 + 7] += bf_hi(u.w);
                    }
                }
            }
        }
        short* basep = &As[rloc * LDSN + p * 32];
        #pragma unroll
        for (int q = 0; q < 4; ++q) {
            short8v nb = { bf16bits(acc[q * 8 + 0]), bf16bits(acc[q * 8 + 1]),
                           bf16bits(acc[q * 8 + 2]), bf16bits(acc[q * 8 + 3]),
                           bf16bits(acc[q * 8 + 4]), bf16bits(acc[q * 8 + 5]),
                           bf16bits(acc[q * 8 + 6]), bf16bits(acc[q * 8 + 7]) };
            *(short8v*)(basep + q * 8) = nb;
        }
    }
    __syncthreads();

    // MFMA phase: wave w owns rows w*16..w*16+15
    const int w  = tid >> 6;
    const int l  = tid & 63;
    const int cg = l & 15;
    const int rg = l >> 4;

    short8v a[8];
    const short* arow = &As[(w * 16 + cg) * LDSN + rg * 8];
    #pragma unroll
    for (int s = 0; s < 4; ++s) a[s] = *(const short8v*)(arow + s * 32);
    int srow = d * PER_DEG + rows0 + w * 16 + cg;
    if (srow >= N_ATOMS) srow = N_ATOMS - 1;
    const short* sp = abf + (size_t)srow * F_DIM + rg * 8;
    #pragma unroll
    for (int s = 0; s < 4; ++s) a[4 + s] = *(const short8v*)(sp + s * 32);

    const short* wtd = wt + (size_t)d * F_DIM * WT_K;
    f32x4 aA[8];
    #pragma unroll
    for (int n = 0; n < 8; ++n) aA[n] = 0.0f;
    #pragma unroll
    for (int s = 0; s < 8; ++s) {
        #pragma unroll
        for (int n = 0; n < 8; ++n) {
            short8v bv = *(const short8v*)(wtd + (n * 16 + cg) * WT_K + s * 32 + rg * 8);
            aA[n] = __builtin_amdgcn_mfma_f32_16x16x32_bf16(a[s], bv, aA[n], 0, 0, 0);
        }
    }

    // epilogue: bias + LayerNorm + plain stores (L2 merges them)
    float biasv[8], gam[8], bet[8];
    #pragma unroll
    for (int n = 0; n < 8; ++n) {
        int col = n * 16 + cg;
        biasv[n] = (d > 0) ? (b[(2 * d - 2) * F_DIM + col] + b[(2 * d - 1) * F_DIM + col])
                           : b[20 * F_DIM + col];
        gam[n] = gamma[col];
        bet[n] = beta[col];
    }
    const int valid = (PER_DEG - rows0 < BM) ? (PER_DEG - rows0) : BM;
    #pragma unroll
    for (int j = 0; j < 4; ++j) {
        const int rl = w * 16 + rg * 4 + j;
        float x[8];
        float s1 = 0.f, s2 = 0.f;
        #pragma unroll
        for (int n = 0; n < 8; ++n) {
            x[n] = aA[n][j] + biasv[n];
            s1 += x[n];
            s2 += x[n] * x[n];
        }
        #pragma unroll
        for (int m = 1; m < 16; m <<= 1) {
            s1 += __shfl_xor(s1, m);
            s2 += __shfl_xor(s2, m);
        }
        float mean = s1 * (1.0f / 128.0f);
        float var  = fmaxf(s2 * (1.0f / 128.0f) - mean * mean, 0.0f);
        float inv  = 1.0f / (sqrtf(var + 1e-5f) + 1e-5f);
        if (rl < valid) {
            float* op = outN + (size_t)(d * PER_DEG + rows0 + rl) * F_DIM;
            #pragma unroll
            for (int n = 0; n < 8; ++n)
                op[n * 16 + cg] = gam[n] * ((x[n] - mean) * inv) + bet[n];
        }
    }
}

// ---------- per-(molecule,degree) bucket sum (45056 blocks, bf16 table) ----
__global__ __launch_bounds__(128) void mol_reduce(
    const short* __restrict__ abf, const int* __restrict__ idx,
    const int* __restrict__ off, const int* __restrict__ hist2,
    short* __restrict__ sums)
{
    const int key = blockIdx.x;           // m * NDEG + d
    const int m   = key / NDEG;
    const int dd  = key - m * NDEG;
    const int c   = threadIdx.x;
    const int base = off[key];
    const int n    = hist2[key];
    float acc = 0.0f;
    #pragma unroll 4
    for (int t = 0; t < n; ++t) {
        int id = idx[base + t];
        acc += bf2f(abf[(size_t)id * F_DIM + c]);
    }
    short* out = sums + (size_t)m * GWT_K;
    out[dd * F_DIM + c] = bf16bits(acc);
    if (c == 0) out[1408 + dd] = bf16bits((float)n);
    if (dd == 0 && c >= 11 && c < 32) out[1408 + c] = 0;
}

// ---------- gat GEMM: outG[4096][128] = sums[4096][1440] @ gwt^T -----------
__global__ __launch_bounds__(256) void gat_gemm(
    const short* __restrict__ sums, const short* __restrict__ gwt,
    float* __restrict__ outG)
{
    const int rows0 = blockIdx.x * 64;
    const int tid = threadIdx.x;
    const int w = tid >> 6, l = tid & 63, cg = l & 15, rg = l >> 4;
    const short* ap = sums + (size_t)(rows0 + w * 16 + cg) * GWT_K + rg * 8;
    f32x4 acc[8];
    #pragma unroll
    for (int n = 0; n < 8; ++n) acc[n] = 0.0f;
    for (int ks = 0; ks < GWT_K / 32; ++ks) {
        short8v av = *(const short8v*)(ap + ks * 32);
        #pragma unroll
        for (int n = 0; n < 8; ++n) {
            short8v bv = *(const short8v*)(gwt + (size_t)(n * 16 + cg) * GWT_K + ks * 32 + rg * 8);
            acc[n] = __builtin_amdgcn_mfma_f32_16x16x32_bf16(av, bv, acc[n], 0, 0, 0);
        }
    }
    #pragma unroll
    for (int j = 0; j < 4; ++j) {
        int r = rows0 + w * 16 + rg * 4 + j;
        #pragma unroll
        for (int n = 0; n < 8; ++n)
            outG[(size_t)r * F_DIM + n * 16 + cg] = acc[n][j];
    }
}

// =================== legacy fallback (R1 kernel) ===========================
__global__ void prep_wt_full(const float* __restrict__ W, const float* __restrict__ gW,
                             short* __restrict__ wt) {
    int idx = blockIdx.x * blockDim.x + threadIdx.x;
    const int total = NDEG * F_DIM * WT_K_L;
    if (idx >= total) return;
    int d   = idx / (F_DIM * WT_K_L);
    int rem = idx % (F_DIM * WT_K_L);
    int c   = rem / WT_K_L;
    int k   = rem % WT_K_L;
    float v;
    if (k < 256) {
        if (d == 0) v = (k < 128) ? 0.0f : W[20 * 16384 + (k - 128) * F_DIM + c];
        else {
            int wi = (k < 128) ? (2 * (d - 1)) : (2 * (d - 1) + 1);
            v = W[wi * 16384 + (k & 127) * F_DIM + c];
        }
    } else {
        int gi = (d == 0) ? 10 : (d - 1);
        v = gW[gi * 16384 + (k - 256) * F_DIM + c];
    }
    wt[idx] = bf16bits(v);
}

__global__ __launch_bounds__(256, 2) void fused_legacy(
    const float* __restrict__ atoms,
    const int* __restrict__ membership, AdjPtrs adj,
    const short* __restrict__ wt, const float* __restrict__ b,
    const float* __restrict__ gb, const float* __restrict__ gamma,
    const float* __restrict__ beta, float* __restrict__ outN, float* __restrict__ outG)
{
    __shared__ short As[BM * LDST_L];
    const int bid = blockIdx.x, d = bid / BPD, rb = bid % BPD;
    const int rows0 = rb * BM, tid = threadIdx.x;
    {
        const int rloc = tid >> 2, p = tid & 3;
        const int grow = rows0 + rloc;
        const bool rv = grow < PER_DEG;
        short* basep = &As[rloc * LDST_L + p * 32];
        f32x4 accn[8], selfv[8];
        #pragma unroll
        for (int q = 0; q < 8; ++q) { accn[q] = 0.0f; selfv[q] = 0.0f; }
        const f32x4* atomsv = (const f32x4*)atoms;
        if (rv) {
            if (d > 0) {
                const int* ar = adj.p[d - 1] + (size_t)grow * d;
                int idxs[MAXD];
                #pragma unroll
                for (int j = 0; j < MAXD; ++j) idxs[j] = (j < d) ? ar[j] : 0;
                #pragma unroll
                for (int j = 0; j < MAXD; ++j) if (j < d) {
                    const f32x4* s = atomsv + (size_t)idxs[j] * 32 + p * 8;
                    #pragma unroll
                    for (int q = 0; q < 8; ++q) accn[q] += s[q];
                }
            }
            const f32x4* s = atomsv + (size_t)(d * PER_DEG + grow) * 32 + p * 8;
            #pragma unroll
            for (int q = 0; q < 8; ++q) selfv[q] = s[q];
        }
        #pragma unroll
        for (int q = 0; q < 8; ++q) {
            short4v nb = { bf16bits(accn[q][0]), bf16bits(accn[q][1]),
                           bf16bits(accn[q][2]), bf16bits(accn[q][3]) };
            short4v sv = { bf16bits(selfv[q][0]), bf16bits(selfv[q][1]),
                           bf16bits(selfv[q][2]), bf16bits(selfv[q][3]) };
            *(short4v*)(basep + q * 4) = nb;
            *(short4v*)(basep + 128 + q * 4) = sv;
        }
    }
    __syncthreads();
    const int w = tid >> 6, l = tid & 63, cg = l & 15, rg = l >> 4;
    short8v a[8];
    const short* arow = &As[(w * 16 + cg) * LDST_L + rg * 8];
    #pragma unroll
    for (int s = 0; s < 8; ++s) a[s] = *(const short8v*)(arow + s * 32);
    const short* wtd = wt + (size_t)d * F_DIM * WT_K_L;
    f32x4 aA[8], aG[8];
    #pragma unroll
    for (int n = 0; n < 8; ++n) { aA[n] = 0.0f; aG[n] = 0.0f; }
    #pragma unroll
    for (int s = 0; s < 8; ++s) {
        #pragma unroll
        for (int n = 0; n < 8; ++n) {
            short8v bv = *(const short8v*)(wtd + (n * 16 + cg) * WT_K_L + s * 32 + rg * 8);
            aA[n] = __builtin_amdgcn_mfma_f32_16x16x32_bf16(a[s], bv, aA[n], 0, 0, 0);
        }
    }
    #pragma unroll
    for (int s = 0; s < 4; ++s) {
        #pragma unroll
        for (int n = 0; n < 8; ++n) {
            short8v bv = *(const short8v*)(wtd + (n * 16 + cg) * WT_K_L + 256 + s * 32 + rg * 8);
            aG[n] = __builtin_amdgcn_mfma_f32_16x16x32_bf16(a[4 + s], bv, aG[n], 0, 0, 0);
        }
    }
    const int gi = (d == 0) ? 10 : (d - 1);
    float biasv[8], gbv[8], gam[8], bet[8];
    #pragma unroll
    for (int n = 0; n < 8; ++n) {
        int col = n * 16 + cg;
        biasv[n] = (d > 0) ? (b[(2*d-2)*F_DIM+col] + b[(2*d-1)*F_DIM+col]) : b[20*F_DIM+col];
        gbv[n] = gb[gi * F_DIM + col];
        gam[n] = gamma[col]; bet[n] = beta[col];
    }
    const int valid = (PER_DEG - rows0 < BM) ? (PER_DEG - rows0) : BM;
    #pragma unroll
    for (int j = 0; j < 4; ++j) {
        const int rl = w * 16 + rg * 4 + j;
        float x[8], s1 = 0.f, s2 = 0.f;
        #pragma unroll
        for (int n = 0; n < 8; ++n) { x[n] = aA[n][j] + biasv[n]; s1 += x[n]; s2 += x[n]*x[n]; }
        #pragma unroll
        for (int m = 1; m < 16; m <<= 1) { s1 += __shfl_xor(s1, m); s2 += __shfl_xor(s2, m); }
        float mean = s1 * (1.0f/128.0f);
        float var  = fmaxf(s2 * (1.0f/128.0f) - mean*mean, 0.0f);
        float inv  = 1.0f / (sqrtf(var + 1e-5f) + 1e-5f);
        if (rl < valid) {
            const int growi = d * PER_DEG + rows0 + rl;
            float* op = outN + (size_t)growi * F_DIM;
            float* gp = outG + (size_t)membership[growi] * F_DIM;
            #pragma unroll
            for (int n = 0; n < 8; ++n) {
                int col = n * 16 + cg;
                op[col] = gam[n] * ((x[n] - mean) * inv) + bet[n];
                atomicAdd(&gp[col], aG[n][j] + gbv[n]);
            }
        }
    }
}

// ===========================================================================
extern "C" void kernel_launch(void* const* d_in, const int* in_sizes, int n_in,
                              void* d_out, int out_size, void* d_ws, size_t ws_size,
                              hipStream_t stream) {
    const float* atoms      = (const float*)d_in[0];
    const int*   membership = (const int*)d_in[2];
    AdjPtrs adj;
    for (int i = 0; i < MAXD; ++i) adj.p[i] = (const int*)d_in[3 + i];
    const float* W     = (const float*)d_in[13];
    const float* b     = (const float*)d_in[14];
    const float* gW    = (const float*)d_in[15];
    const float* gb    = (const float*)d_in[16];
    const float* gamma = (const float*)d_in[17];
    const float* beta  = (const float*)d_in[18];

    float* outN = (float*)d_out;
    float* outG = outN + (size_t)N_ATOMS * F_DIM;

    auto al = [](size_t x) { return (x + 255) & ~(size_t)255; };
    const size_t sz_wt   = al((size_t)NDEG * F_DIM * WT_K * 2);    // 720 KB
    const size_t sz_gwt  = al((size_t)F_DIM * GWT_K * 2);          // 360 KB
    const size_t sz_h    = al((size_t)BATCH * NDEG * 4);           // 180 KB
    const size_t sz_idx  = al((size_t)N_ATOMS * 4);                // 2.2 MB
    const size_t sz_sums = al((size_t)BATCH * GWT_K * 2);          // 11.8 MB
    const size_t sz_abf  = (size_t)N_ATOMS * F_DIM * 2;            // 140.8 MB

    size_t o = 0;
    short* wt    = (short*)((char*)d_ws + o); o += sz_wt;
    short* gwt   = (short*)((char*)d_ws + o); o += sz_gwt;
    int*   hist2 = (int*)  ((char*)d_ws + o); o += sz_h;
    int*   offa  = (int*)  ((char*)d_ws + o); o += sz_h;
    int*   cura  = (int*)  ((char*)d_ws + o); o += sz_h;
    int*   idx   = (int*)  ((char*)d_ws + o); o += sz_idx;
    short* sums  = (short*)((char*)d_ws + o); o += sz_sums;
    short* abf   = (short*)((char*)d_ws + o); o += sz_abf;

    if (ws_size >= o) {
        prep_wt_main<<<(NDEG * F_DIM * WT_K + 255) / 256, 256, 0, stream>>>(W, wt);
        prep_gwt<<<(F_DIM * GWT_K + 255) / 256, 256, 0, stream>>>(gW, gb, gwt);
        hipMemsetAsync(hist2, 0, (size_t)BATCH * NDEG * 4, stream);
        to_bf16<<<2048, 256, 0, stream>>>(atoms, abf);
        hist_kernel<<<(N_ATOMS + 255) / 256, 256, 0, stream>>>(membership, hist2);
        scan_offsets<<<1, 1024, 0, stream>>>(hist2, offa, cura);
        scatter_kernel<<<(N_ATOMS + 255) / 256, 256, 0, stream>>>(membership, cura, idx);
        fused_deg<<<NDEG * BPD, 256, 0, stream>>>(abf, adj, wt, b, gamma, beta, outN);
        mol_reduce<<<BATCH * NDEG, 128, 0, stream>>>(abf, idx, offa, hist2, sums);
        gat_gemm<<<BATCH / 64, 256, 0, stream>>>(sums, gwt, outG);
    } else {
        // ---- legacy fallback (atomics path, f32 reads) ----
        short* lwt = (short*)d_ws;
        prep_wt_full<<<(NDEG * F_DIM * WT_K_L + 255) / 256, 256, 0, stream>>>(W, gW, lwt);
        hipMemsetAsync(outG, 0, (size_t)BATCH * F_DIM * 4, stream);
        fused_legacy<<<NDEG * BPD, 256, 0, stream>>>(atoms, membership, adj, lwt,
                                                     b, gb, gamma, beta, outN, outG);
    }
}